// Round 8
// baseline (483.992 us; speedup 1.0000x reference)
//
#include <hip/hip_runtime.h>
#include <hip/hip_bf16.h>
#include <stdint.h>

// Problem constants (fixed by setup_inputs)
#define TM 16384   // B rows of input
#define TN 4096    // O centers
#define TK 1024    // I feature dim

#define NT (TK / 64)   // 16 K-tiles per output tile
#define JT 4           // center tiles per block (persistent along O)

typedef __attribute__((ext_vector_type(8))) short bf16x8;
typedef __attribute__((ext_vector_type(4))) float f32x4;

static __device__ __forceinline__ ushort f2bf(float x) {
    __hip_bfloat16 h = __float2bfloat16(x);
    return *reinterpret_cast<ushort*>(&h);
}

// Convert one fp32 row (TK elems) to bf16 and emit its sum of squares.
__global__ __launch_bounds__(256) void rowsq_cvt(const float* __restrict__ src,
                                                 ushort* __restrict__ dst,
                                                 float* __restrict__ sq) {
    const int row = blockIdx.x;
    const int t = threadIdx.x;
    const size_t base = (size_t)row * TK + (size_t)t * 4;
    const f32x4 v = __builtin_nontemporal_load((const f32x4*)(src + base));
    float s = v.x * v.x + v.y * v.y + v.z * v.z + v.w * v.w;

    ushort4 b;
    b.x = f2bf(v.x); b.y = f2bf(v.y); b.z = f2bf(v.z); b.w = f2bf(v.w);
    *(ushort4*)(dst + base) = b;

#pragma unroll
    for (int off = 32; off > 0; off >>= 1) s += __shfl_down(s, off);

    __shared__ float red[4];
    const int lane = t & 63, wave = t >> 6;
    if (lane == 0) red[wave] = s;
    __syncthreads();
    if (t == 0) sq[row] = red[0] + red[1] + red[2] + red[3];
}

// f[o] = -1/(2*sigma^2), sigma = exp(log_sigma)
__global__ __launch_bounds__(256) void scale_k(const float* __restrict__ ls,
                                               float* __restrict__ f) {
    const int i = blockIdx.x * 256 + threadIdx.x;
    if (i < TN) f[i] = -0.5f * expf(-2.0f * ls[i]);
}

// ---- persistent 8-phase 256x256 bf16 MFMA GEMM, 4 waves, fused RBF epilogue ----
// Round-8 restructure: 4 waves (2x2), 128x128 per wave, frag double-buffering
// so ds_reads are issued 1-2 phases before their MFMA cluster and serviced
// DURING the previous cluster (round-7 finding: phase = LDS-service + MFMA
// serialized -> MfmaUtil capped at ~33%). Register budget: acc 256 + afx2 64
// + bf 64 ~ 400/wave; 1 wave/SIMD so <=512 is fine.
// A-operand = centers panel, B-operand = input panel (contiguous f32x4 C
// stores - round-6). LDS: 4 panels 256x64 bf16, 2-bit XOR swizzle (bits 5,6
// from row bits 2,3); k-offset folded by XOR not add (round-4). Compiler
// emits exact lgkmcnt for its own ds_reads; sched_barrier(0) pins loads to
// their phase. vmcnt guards: 16 staging insts/pair -> vmcnt(8) at R4/R8.

#define STAGEQ(PAN, SRC, Q)                                                    \
    __builtin_amdgcn_global_load_lds(                                          \
        (const __attribute__((address_space(1))) void*)((SRC) + (size_t)(Q) * 32 * TK), \
        (__attribute__((address_space(3))) void*)((PAN) + (Q) * 2048 + wbase), \
        16, 0, 0)

#define STAGE4(PAN, SRC, H) do {                                               \
    STAGEQ(PAN, SRC, (H) * 4 + 0); STAGEQ(PAN, SRC, (H) * 4 + 1);              \
    STAGEQ(PAN, SRC, (H) * 4 + 2); STAGEQ(PAN, SRC, (H) * 4 + 3);              \
} while (0)

// Staging-stream sources. A-stream = CENTERS (advances tile per j, wraps &63
// for j=3 tail; wrapped data staged but never consumed). B-stream = INPUT
// panel, same every j (wraps &15).
#define ASRC(S) (gAl + (size_t)(((S) & 63) >> 4) * (256 * (size_t)TK) + (size_t)((S) & 15) * 64)
#define BSRC(S) (gBl + (size_t)((S) & 15) * 64)

// A-quadrant (4 m-frags x 2 k) -> DST; rows rowA + QM*64 + i*16
#define READAQ(DST, PAN, QM) do {                                              \
    _Pragma("unroll") for (int _i = 0; _i < 4; ++_i)                           \
    _Pragma("unroll") for (int _k = 0; _k < 2; ++_k)                           \
        DST[_i][_k] = *(const bf16x8*)((PAN) +                                 \
            (size_t)(rowA + (QM) * 64 + _i * 16) * 64 + (cX ^ (_k * 32)));     \
} while (0)

// B-half NH (4 n-frags x 2 k) -> bf[NH*4 ..]; rows rowB + NH*64 + n*16
#define READBH(PAN, NH) do {                                                   \
    _Pragma("unroll") for (int _n = 0; _n < 4; ++_n)                           \
    _Pragma("unroll") for (int _k = 0; _k < 2; ++_k)                           \
        bf[(NH) * 4 + _n][_k] = *(const bf16x8*)((PAN) +                       \
            (size_t)(rowB + (NH) * 64 + _n * 16) * 64 + (cX ^ (_k * 32)));     \
} while (0)

// One quadrant cluster: 4m x 4n x 2k = 32 MFMA
#define MFMA32(AF, QM, QN)                                                     \
    _Pragma("unroll") for (int _i = 0; _i < 4; ++_i)                           \
    _Pragma("unroll") for (int _n = 0; _n < 4; ++_n)                           \
    _Pragma("unroll") for (int _k = 0; _k < 2; ++_k)                           \
        acc[(QM) * 4 + _i][(QN) * 4 + _n] =                                    \
            __builtin_amdgcn_mfma_f32_16x16x32_bf16(                           \
                AF[_i][_k], bf[(QN) * 4 + _n][_k],                             \
                acc[(QM) * 4 + _i][(QN) * 4 + _n], 0, 0, 0)

#define PH_SYNC do {                                                           \
    __builtin_amdgcn_s_barrier();                                              \
    __builtin_amdgcn_sched_barrier(0);                                         \
    __builtin_amdgcn_s_setprio(1);                                             \
} while (0)

#define PH_END do {                                                            \
    __builtin_amdgcn_s_setprio(0);                                             \
    __builtin_amdgcn_sched_barrier(0);                                         \
    __builtin_amdgcn_s_barrier();                                              \
} while (0)

#define PH_VM do {                                                             \
    __builtin_amdgcn_s_setprio(0);                                             \
    asm volatile("s_waitcnt vmcnt(8)" ::: "memory");                           \
    __builtin_amdgcn_sched_barrier(0);                                         \
} while (0)

#define PH_BAR do {                                                            \
    __builtin_amdgcn_sched_barrier(0);                                         \
    __builtin_amdgcn_s_barrier();                                              \
} while (0)

__global__ __launch_bounds__(256, 1) void rbf_gemm(
        const ushort* __restrict__ Cb,  // centers bf16 [TN][TK]
        const ushort* __restrict__ Xb,  // input   bf16 [TM][TK]
        const float* __restrict__ xsq,
        const float* __restrict__ csq,
        const float* __restrict__ fsc,
        float* __restrict__ out) {
    __shared__ __align__(16) ushort lds[65536];  // 128 KiB

    // 256 persistent blocks (1/CU). Per XCD (32 consecutive wg): 8 input
    // panels x 4 jbase groups; blocks sharing a jbase group stream the same
    // 4 center tiles (L2 reuse).
    const int bid = blockIdx.x;
    const int wg = (bid & 7) * 32 + (bid >> 3);
    const int bm = wg >> 2;            // 64 input tiles (rows of out)
    const int jbase = (wg & 3) * 4;    // first of 4 center tiles (cols of out)
    const int rowx0 = bm * 256;

    const int tid = threadIdx.x;
    const int lane = tid & 63, wave = tid >> 6;
    const int wr = wave >> 1, wc = wave & 1;      // 2x2 waves, 128x128 out each
    const int lrow = lane & 15, lhi = lane >> 4;  // MFMA fragment coords
    // 2-bit swizzled ds_read col (elems): row bits 2,3 (= lrow bits 2,3)
    const int cX = (lhi * 8) ^ ((lrow & 4) << 2) ^ ((lrow & 8) << 2);
    const int rowA = wr * 128 + lrow;             // centers panel row
    const int rowB = wc * 128 + lrow;             // input panel row
    const int wbase = wave * 512;                 // elems: wave's 1KB slice per inst

    // Per-lane staging source: linear LDS slot -> inverse-swizzled global col.
    // One STAGEQ inst covers 32 rows: srow = tid>>3; r&4 = tid&32, r&8 = tid&64.
    const int srow = tid >> 3;
    const int scol = ((tid & 7) * 8) ^ ((tid & 32) >> 1) ^ ((tid & 64) >> 1);
    const ushort* gAl = Cb + (size_t)(jbase * 256 + srow) * TK + scol;  // centers
    const ushort* gBl = Xb + (size_t)(rowx0 + srow) * TK + scol;        // input

    ushort* pA0 = lds;           // buf0 A (even K-tiles)
    ushort* pB0 = lds + 16384;   // buf0 B
    ushort* pA1 = lds + 32768;   // buf1 A (odd K-tiles)
    ushort* pB1 = lds + 49152;   // buf1 B

    bf16x8 af0[4][2], af1[4][2];  // A quadrants, double-buffered
    bf16x8 bf[8][2];              // full B tile (two halves, rotated in place)

    // Prologue: stage tile0 B+A and tile1 B (24 insts); vmcnt(8) retires
    // B(0)+A(0), leaves B(1) in flight. Then prime tile0's first frags.
    STAGE4(pB0, BSRC(0), 0); STAGE4(pB0, BSRC(0), 1);
    STAGE4(pA0, ASRC(0), 0); STAGE4(pA0, ASRC(0), 1);
    STAGE4(pB1, BSRC(1), 0); STAGE4(pB1, BSRC(1), 1);
    asm volatile("s_waitcnt vmcnt(8)" ::: "memory");
    __builtin_amdgcn_s_barrier();
    READAQ(af0, pA0, 0); READBH(pB0, 0);

#pragma unroll 1
    for (int j = 0; j < JT; ++j) {
        f32x4 acc[8][8];
#pragma unroll
        for (int m = 0; m < 8; ++m)
#pragma unroll
            for (int n = 0; n < 8; ++n)
                acc[m][n] = (f32x4){0.f, 0.f, 0.f, 0.f};

#pragma unroll 1
        for (int t = 0; t < NT; t += 2) {
            const int s = j * NT + t;  // staging stream position

            // ---- tile t (buf0) ----
            // R1: Q00 consumes af0/bf[0..3] (primed R8-late / prologue);
            //     prefetch af1 (used R3/R4) + bf-high (used R2).
            READAQ(af1, pA0, 1); READBH(pB0, 1);
            STAGE4(pA1, ASRC(s + 1), 0);
            PH_SYNC; MFMA32(af0, 0, 0); PH_END;
            // R2: Q01
            STAGE4(pA1, ASRC(s + 1), 1);
            PH_SYNC; MFMA32(af0, 0, 1); PH_END;
            // R3: Q10
            STAGE4(pB0, BSRC(s + 2), 0);
            PH_SYNC; MFMA32(af1, 1, 0); PH_END;
            // R4: Q11; vmcnt(8) lands A(s+1)->pA1 (and B(s+1)->pB1 older);
            //     then prefetch next tile's af0 + bf-low during barrier window.
            STAGE4(pB0, BSRC(s + 2), 1);
            PH_SYNC; MFMA32(af1, 1, 1);
            PH_VM;
            READAQ(af0, pA1, 0); READBH(pB1, 0);
            PH_BAR;

            // ---- tile t+1 (buf1) ----
            // R5: Q00; prefetch af1 (R7/R8) + bf-high (R6).
            READAQ(af1, pA1, 1); READBH(pB1, 1);
            STAGE4(pA0, ASRC(s + 2), 0);
            PH_SYNC; MFMA32(af0, 0, 0); PH_END;
            // R6: Q01
            STAGE4(pA0, ASRC(s + 2), 1);
            PH_SYNC; MFMA32(af0, 0, 1); PH_END;
            // R7: Q10
            STAGE4(pB1, BSRC(s + 3), 0);
            PH_SYNC; MFMA32(af1, 1, 0); PH_END;
            // R8: Q11; vmcnt(8) lands A(s+2)->pA0, B(s+2)->pB0;
            //     prefetch next pair's (or next j's) af0 + bf-low.
            STAGE4(pB1, BSRC(s + 3), 1);
            PH_SYNC; MFMA32(af1, 1, 1);
            PH_VM;
            READAQ(af0, pA0, 0); READBH(pB0, 0);
            PH_BAR;
        }

        // Epilogue for center tile j (runs while next tile's frag reads and
        // staging loads are in flight). acc[m][n][jj]:
        //   o = o0 + m*16 + lhi*4 + jj (centers), b = b0 + n*16 + lrow (input)
        const int o0 = (jbase + j) * 256 + wr * 128;
        const int b0 = rowx0 + wc * 128;
#pragma unroll
        for (int m = 0; m < 8; ++m) {
            const int o4 = o0 + m * 16 + lhi * 4;
            const f32x4 cs4 = *(const f32x4*)(csq + o4);
            const f32x4 fs4 = *(const f32x4*)(fsc + o4);
#pragma unroll
            for (int n = 0; n < 8; ++n) {
                const int b = b0 + n * 16 + lrow;
                const float xs = xsq[b];
                f32x4 v;
#pragma unroll
                for (int jj = 0; jj < 4; ++jj) {
                    float d2 = fmaxf(xs + cs4[jj] - 2.0f * acc[m][n][jj], 0.0f);
                    v[jj] = __expf(fs4[jj] * d2);
                }
                *(f32x4*)(out + (size_t)b * TN + o4) = v;
            }
        }
    }
}

extern "C" void kernel_launch(void* const* d_in, const int* in_sizes, int n_in,
                              void* d_out, int out_size, void* d_ws, size_t ws_size,
                              hipStream_t stream) {
    const float* inp = (const float*)d_in[0];  // [TM, TK]
    const float* ctr = (const float*)d_in[1];  // [TN, TK]
    const float* ls  = (const float*)d_in[2];  // [TN]
    float* out = (float*)d_out;

    // workspace layout (~42 MB)
    ushort* Abf = (ushort*)d_ws;
    ushort* Bbf = Abf + (size_t)TM * TK;
    float* xsq = (float*)(Bbf + (size_t)TN * TK);
    float* csq = xsq + TM;
    float* fsc = csq + TN;

    rowsq_cvt<<<TM, 256, 0, stream>>>(inp, Abf, xsq);
    rowsq_cvt<<<TN, 256, 0, stream>>>(ctr, Bbf, csq);
    scale_k<<<(TN + 255) / 256, 256, 0, stream>>>(ls, fsc);

    rbf_gemm<<<256, 256, 0, stream>>>(Bbf, Abf, xsq, csq, fsc, out);
}

// Round 9
// 361.517 us; speedup vs baseline: 1.3388x; 1.3388x over previous
//
#include <hip/hip_runtime.h>
#include <hip/hip_bf16.h>
#include <stdint.h>

// Problem constants (fixed by setup_inputs)
#define TM 16384   // B rows of input
#define TN 4096    // O centers
#define TK 1024    // I feature dim

#define NT (TK / 64)   // 16 K-tiles per output tile
#define JT 4           // center tiles per block (persistent along O)

typedef __attribute__((ext_vector_type(8))) short bf16x8;
typedef __attribute__((ext_vector_type(4))) float f32x4;

static __device__ __forceinline__ ushort f2bf(float x) {
    __hip_bfloat16 h = __float2bfloat16(x);
    return *reinterpret_cast<ushort*>(&h);
}

// Convert one fp32 row (TK elems) to bf16 and emit its sum of squares.
__global__ __launch_bounds__(256) void rowsq_cvt(const float* __restrict__ src,
                                                 ushort* __restrict__ dst,
                                                 float* __restrict__ sq) {
    const int row = blockIdx.x;
    const int t = threadIdx.x;
    const size_t base = (size_t)row * TK + (size_t)t * 4;
    const f32x4 v = __builtin_nontemporal_load((const f32x4*)(src + base));
    float s = v.x * v.x + v.y * v.y + v.z * v.z + v.w * v.w;

    ushort4 b;
    b.x = f2bf(v.x); b.y = f2bf(v.y); b.z = f2bf(v.z); b.w = f2bf(v.w);
    *(ushort4*)(dst + base) = b;

#pragma unroll
    for (int off = 32; off > 0; off >>= 1) s += __shfl_down(s, off);

    __shared__ float red[4];
    const int lane = t & 63, wave = t >> 6;
    if (lane == 0) red[wave] = s;
    __syncthreads();
    if (t == 0) sq[row] = red[0] + red[1] + red[2] + red[3];
}

// f[o] = -1/(2*sigma^2), sigma = exp(log_sigma)
__global__ __launch_bounds__(256) void scale_k(const float* __restrict__ ls,
                                               float* __restrict__ f) {
    const int i = blockIdx.x * 256 + threadIdx.x;
    if (i < TN) f[i] = -0.5f * expf(-2.0f * ls[i]);
}

// ---- persistent 8-phase 256x256 bf16 MFMA GEMM, 4 waves, AGPR accumulator ----
// Round-9: acc[8][8] (256 f32/lane) FORCED into AGPRs via inline-asm MFMA with
// "+a" constraint (round-8 lesson: arch-VGPRs cap at 256; compiler kept acc in
// VGPRs and spilled ~750MB to scratch). Frags+addressing live in VGPRs (~190).
// 4 waves = 1 wave/SIMD -> 512-reg budget/wave. All 32 ds_reads of a tile
// issue at R1/R5-start (AFTER the barrier that follows all waves' vmcnt -
// fixes round-8's formally racy pre-barrier reads); Q00's 16 are waited on,
// the other 16 are serviced during the MFMA clusters (round-7 finding: phase-
// serialized LDS service capped MfmaUtil at ~33%). B staging moved to R4/R8
// (both halves) widening read-issue -> overwrite-landing gap to >=3 phases.
// vmcnt(8) at R4/R8: outstanding = prevB(8)+curA(8)+curB(8)=24 -> retires
// prevB+curA, leaves curB. A-operand = centers (contiguous f32x4 C stores,
// round-6). 2-bit XOR swizzle, k-offset folded by XOR not add (round-4).

#define STAGEQ(PAN, SRC, Q)                                                    \
    __builtin_amdgcn_global_load_lds(                                          \
        (const __attribute__((address_space(1))) void*)((SRC) + (size_t)(Q) * 32 * TK), \
        (__attribute__((address_space(3))) void*)((PAN) + (Q) * 2048 + wbase), \
        16, 0, 0)

#define STAGE4(PAN, SRC, H) do {                                               \
    STAGEQ(PAN, SRC, (H) * 4 + 0); STAGEQ(PAN, SRC, (H) * 4 + 1);              \
    STAGEQ(PAN, SRC, (H) * 4 + 2); STAGEQ(PAN, SRC, (H) * 4 + 3);              \
} while (0)

// A-stream = CENTERS (advances tile per j, wraps &63 for j=3 tail; wrapped
// data staged but never consumed). B-stream = INPUT panel (wraps &15).
#define ASRC(S) (gAl + (size_t)(((S) & 63) >> 4) * (256 * (size_t)TK) + (size_t)((S) & 15) * 64)
#define BSRC(S) (gBl + (size_t)((S) & 15) * 64)

// A-quadrant QM (4 m-frags x 2 k) -> DST
#define READAQ(DST, PAN, QM) do {                                              \
    _Pragma("unroll") for (int _i = 0; _i < 4; ++_i)                           \
    _Pragma("unroll") for (int _k = 0; _k < 2; ++_k)                           \
        DST[_i][_k] = *(const bf16x8*)((PAN) +                                 \
            (size_t)(rowA + (QM) * 64 + _i * 16) * 64 + (cX ^ (_k * 32)));     \
} while (0)

// B-half NH (4 n-frags x 2 k) -> bf[NH*4 ..]
#define READBH(PAN, NH) do {                                                   \
    _Pragma("unroll") for (int _n = 0; _n < 4; ++_n)                           \
    _Pragma("unroll") for (int _k = 0; _k < 2; ++_k)                           \
        bf[(NH) * 4 + _n][_k] = *(const bf16x8*)((PAN) +                       \
            (size_t)(rowB + (NH) * 64 + _n * 16) * 64 + (cX ^ (_k * 32)));     \
} while (0)

// MFMA with accumulator pinned to AGPRs.
#define MFMA1(C, A, B)                                                         \
    asm volatile("v_mfma_f32_16x16x32_bf16 %0, %1, %2, %0"                     \
                 : "+a"(C) : "v"(A), "v"(B))

// One quadrant cluster: 4m x 4n x 2k = 32 MFMA
#define MFMA32(AF, QM, QN)                                                     \
    _Pragma("unroll") for (int _i = 0; _i < 4; ++_i)                           \
    _Pragma("unroll") for (int _n = 0; _n < 4; ++_n)                           \
    _Pragma("unroll") for (int _k = 0; _k < 2; ++_k)                           \
        MFMA1(acc[(QM) * 4 + _i][(QN) * 4 + _n],                               \
              AF[_i][_k], bf[(QN) * 4 + _n][_k])

#define PH_SYNC do {                                                           \
    __builtin_amdgcn_sched_barrier(0);                                         \
    __builtin_amdgcn_s_barrier();                                              \
    __builtin_amdgcn_sched_barrier(0);                                         \
    __builtin_amdgcn_s_setprio(1);                                             \
} while (0)

#define PH_END do {                                                            \
    __builtin_amdgcn_s_setprio(0);                                             \
    __builtin_amdgcn_sched_barrier(0);                                         \
    __builtin_amdgcn_s_barrier();                                              \
} while (0)

#define PH_END_VM do {                                                         \
    __builtin_amdgcn_s_setprio(0);                                             \
    asm volatile("s_waitcnt vmcnt(8)" ::: "memory");                           \
    __builtin_amdgcn_sched_barrier(0);                                         \
    __builtin_amdgcn_s_barrier();                                              \
} while (0)

__global__ __launch_bounds__(256, 1) void rbf_gemm(
        const ushort* __restrict__ Cb,  // centers bf16 [TN][TK]
        const ushort* __restrict__ Xb,  // input   bf16 [TM][TK]
        const float* __restrict__ xsq,
        const float* __restrict__ csq,
        const float* __restrict__ fsc,
        float* __restrict__ out) {
    __shared__ __align__(16) ushort lds[65536];  // 128 KiB

    // 256 persistent blocks (1/CU). Per XCD (32 consecutive wg): 8 input
    // panels x 4 jbase groups; blocks sharing a jbase group stream the same
    // 4 center tiles (L2 reuse).
    const int bid = blockIdx.x;
    const int wg = (bid & 7) * 32 + (bid >> 3);
    const int bm = wg >> 2;            // 64 input tiles (rows of out)
    const int jbase = (wg & 3) * 4;    // first of 4 center tiles (cols of out)
    const int rowx0 = bm * 256;

    const int tid = threadIdx.x;
    const int lane = tid & 63, wave = tid >> 6;
    const int wr = wave >> 1, wc = wave & 1;      // 2x2 waves, 128x128 out each
    const int lrow = lane & 15, lhi = lane >> 4;  // MFMA fragment coords
    const int cX = (lhi * 8) ^ ((lrow & 4) << 2) ^ ((lrow & 8) << 2);
    const int rowA = wr * 128 + lrow;             // centers panel row
    const int rowB = wc * 128 + lrow;             // input panel row
    const int wbase = wave * 512;                 // elems: wave's 1KB slice per inst

    // Per-lane staging source: linear LDS slot -> inverse-swizzled global col.
    const int srow = tid >> 3;
    const int scol = ((tid & 7) * 8) ^ ((tid & 32) >> 1) ^ ((tid & 64) >> 1);
    const ushort* gAl = Cb + (size_t)(jbase * 256 + srow) * TK + scol;  // centers
    const ushort* gBl = Xb + (size_t)(rowx0 + srow) * TK + scol;        // input

    ushort* pA0 = lds;           // buf0 A (even K-tiles)
    ushort* pB0 = lds + 16384;   // buf0 B
    ushort* pA1 = lds + 32768;   // buf1 A (odd K-tiles)
    ushort* pB1 = lds + 49152;   // buf1 B

    bf16x8 af0[4][2], af1[4][2];  // A quadrants, double-buffered
    bf16x8 bf[8][2];              // full B tile for this wave

    // Prologue: stage B(0), A(0), B(1) (24 insts); vmcnt(8) retires B(0)+A(0),
    // leaves B(1) in flight.
    STAGE4(pB0, BSRC(0), 0); STAGE4(pB0, BSRC(0), 1);
    STAGE4(pA0, ASRC(0), 0); STAGE4(pA0, ASRC(0), 1);
    STAGE4(pB1, BSRC(1), 0); STAGE4(pB1, BSRC(1), 1);
    asm volatile("s_waitcnt vmcnt(8)" ::: "memory");
    __builtin_amdgcn_s_barrier();

#pragma unroll 1
    for (int j = 0; j < JT; ++j) {
        f32x4 acc[8][8];
#pragma unroll
        for (int m = 0; m < 8; ++m)
#pragma unroll
            for (int n = 0; n < 8; ++n)
                acc[m][n] = (f32x4){0.f, 0.f, 0.f, 0.f};

#pragma unroll 1
        for (int t = 0; t < NT; t += 2) {
            const int s = j * NT + t;  // staging stream position

            // ---- tile t (buf0) ----
            // R1: ALL tile-t reads (af0,bf_lo critical for Q00; af1,bf_hi
            //     serviced under R1-R2 MFMA). No staging this phase.
            READAQ(af0, pA0, 0); READBH(pB0, 0);
            READAQ(af1, pA0, 1); READBH(pB0, 1);
            PH_SYNC; MFMA32(af0, 0, 0); PH_END;
            // R2
            STAGE4(pA1, ASRC(s + 1), 0);
            PH_SYNC; MFMA32(af0, 0, 1); PH_END;
            // R3
            STAGE4(pA1, ASRC(s + 1), 1);
            PH_SYNC; MFMA32(af1, 1, 0); PH_END;
            // R4: both B(s+2) halves; vmcnt(8) retires B(s+1)+A(s+1),
            //     leaves B(s+2) in flight.
            STAGE4(pB0, BSRC(s + 2), 0); STAGE4(pB0, BSRC(s + 2), 1);
            PH_SYNC; MFMA32(af1, 1, 1); PH_END_VM;

            // ---- tile t+1 (buf1) ----
            // R5: all tile-(t+1) reads (pA1/pB1 guarded by R4's vmcnt+barrier).
            READAQ(af0, pA1, 0); READBH(pB1, 0);
            READAQ(af1, pA1, 1); READBH(pB1, 1);
            PH_SYNC; MFMA32(af0, 0, 0); PH_END;
            // R6
            STAGE4(pA0, ASRC(s + 2), 0);
            PH_SYNC; MFMA32(af0, 0, 1); PH_END;
            // R7
            STAGE4(pA0, ASRC(s + 2), 1);
            PH_SYNC; MFMA32(af1, 1, 0); PH_END;
            // R8: both B(s+3) halves; vmcnt(8) retires B(s+2)+A(s+2).
            STAGE4(pB1, BSRC(s + 3), 0); STAGE4(pB1, BSRC(s + 3), 1);
            PH_SYNC; MFMA32(af1, 1, 1); PH_END_VM;
        }

        // Epilogue for center tile j (acc read out of AGPRs; next tile's
        // panels already in flight). acc[m][n][jj]:
        //   o = o0 + m*16 + lhi*4 + jj (centers), b = b0 + n*16 + lrow (input)
        const int o0 = (jbase + j) * 256 + wr * 128;
        const int b0 = rowx0 + wc * 128;
#pragma unroll
        for (int m = 0; m < 8; ++m) {
            const int o4 = o0 + m * 16 + lhi * 4;
            const f32x4 cs4 = *(const f32x4*)(csq + o4);
            const f32x4 fs4 = *(const f32x4*)(fsc + o4);
#pragma unroll
            for (int n = 0; n < 8; ++n) {
                const int b = b0 + n * 16 + lrow;
                const float xs = xsq[b];
                f32x4 v;
#pragma unroll
                for (int jj = 0; jj < 4; ++jj) {
                    float d2 = fmaxf(xs + cs4[jj] - 2.0f * acc[m][n][jj], 0.0f);
                    v[jj] = __expf(fs4[jj] * d2);
                }
                *(f32x4*)(out + (size_t)b * TN + o4) = v;
            }
        }
    }
}

extern "C" void kernel_launch(void* const* d_in, const int* in_sizes, int n_in,
                              void* d_out, int out_size, void* d_ws, size_t ws_size,
                              hipStream_t stream) {
    const float* inp = (const float*)d_in[0];  // [TM, TK]
    const float* ctr = (const float*)d_in[1];  // [TN, TK]
    const float* ls  = (const float*)d_in[2];  // [TN]
    float* out = (float*)d_out;

    // workspace layout (~42 MB)
    ushort* Abf = (ushort*)d_ws;
    ushort* Bbf = Abf + (size_t)TM * TK;
    float* xsq = (float*)(Bbf + (size_t)TN * TK);
    float* csq = xsq + TM;
    float* fsc = csq + TN;

    rowsq_cvt<<<TM, 256, 0, stream>>>(inp, Abf, xsq);
    rowsq_cvt<<<TN, 256, 0, stream>>>(ctr, Bbf, csq);
    scale_k<<<(TN + 255) / 256, 256, 0, stream>>>(ls, fsc);

    rbf_gemm<<<256, 256, 0, stream>>>(Bbf, Abf, xsq, csq, fsc, out);
}

// Round 10
// 187.539 us; speedup vs baseline: 2.5808x; 1.9277x over previous
//
#include <hip/hip_runtime.h>
#include <hip/hip_bf16.h>
#include <stdint.h>

// Problem constants (fixed by setup_inputs)
#define TM 16384   // B rows of input
#define TN 4096    // O centers
#define TK 1024    // I feature dim

#define NT (TK / 64)   // 16 K-tiles

typedef __attribute__((ext_vector_type(8))) short bf16x8;
typedef __attribute__((ext_vector_type(4))) float f32x4;

static __device__ __forceinline__ ushort f2bf(float x) {
    __hip_bfloat16 h = __float2bfloat16(x);
    return *reinterpret_cast<ushort*>(&h);
}

// Convert one fp32 row (TK elems) to bf16 and emit its sum of squares.
__global__ __launch_bounds__(256) void rowsq_cvt(const float* __restrict__ src,
                                                 ushort* __restrict__ dst,
                                                 float* __restrict__ sq) {
    const int row = blockIdx.x;
    const int t = threadIdx.x;
    const size_t base = (size_t)row * TK + (size_t)t * 4;
    const f32x4 v = __builtin_nontemporal_load((const f32x4*)(src + base));
    float s = v.x * v.x + v.y * v.y + v.z * v.z + v.w * v.w;

    ushort4 b;
    b.x = f2bf(v.x); b.y = f2bf(v.y); b.z = f2bf(v.z); b.w = f2bf(v.w);
    *(ushort4*)(dst + base) = b;

#pragma unroll
    for (int off = 32; off > 0; off >>= 1) s += __shfl_down(s, off);

    __shared__ float red[4];
    const int lane = t & 63, wave = t >> 6;
    if (lane == 0) red[wave] = s;
    __syncthreads();
    if (t == 0) sq[row] = red[0] + red[1] + red[2] + red[3];
}

// f[o] = -1/(2*sigma^2), sigma = exp(log_sigma)
__global__ __launch_bounds__(256) void scale_k(const float* __restrict__ ls,
                                               float* __restrict__ f) {
    const int i = blockIdx.x * 256 + threadIdx.x;
    if (i < TN) f[i] = -0.5f * expf(-2.0f * ls[i]);
}

// ---- 8-phase 256x256 bf16 MFMA GEMM (NON-persistent), fused RBF epilogue ----
// Round-10 A/B: round-7 kernel with the j-loop (persistence) removed — every
// persistent variant (r5/r6/r7) was slower than non-persistent r2 despite
// better FETCH; the in-stream epilogue's stores stall the next tile's vmcnt
// guard and its wrap arithmetic bloats phases. One 256x256 tile per block,
// single epilogue at block end; stores drain while the next block launches.
// Kept from r6/r7 (independently verified good): operand swap (A=centers ->
// contiguous f32x4 C stores), 2-bit XOR swizzle (row bits 2,3 -> byte bits
// 5,6; k-offset folded by XOR not add — round-4 bug), vmcnt(4) discipline.

#define STAGE(PAN, SRC, H) do {                                                \
    __builtin_amdgcn_global_load_lds(                                          \
        (const __attribute__((address_space(1))) void*)((SRC) + (size_t)(H) * 128 * TK), \
        (__attribute__((address_space(3))) void*)((PAN) + (H) * 8192 + wbase), \
        16, 0, 0);                                                             \
    __builtin_amdgcn_global_load_lds(                                          \
        (const __attribute__((address_space(1))) void*)((SRC) + (size_t)(H) * 128 * TK + 64 * TK), \
        (__attribute__((address_space(3))) void*)((PAN) + (H) * 8192 + 4096 + wbase), \
        16, 0, 0);                                                             \
} while (0)

// Both tiles are fixed per block; stream wraps &15 so tail prefetches re-stage
// in-bounds data that is never consumed (keeps vmcnt schedule uniform).
#define ASRC(S) (gAl + (size_t)((S) & 15) * 64)
#define BSRC(S) (gBl + (size_t)((S) & 15) * 64)

#define READA(PAN, QM) do {                                                    \
    _Pragma("unroll") for (int _i = 0; _i < 4; ++_i)                           \
    _Pragma("unroll") for (int _k = 0; _k < 2; ++_k)                           \
        af[_i][_k] = *(const bf16x8*)((PAN) +                                  \
            (size_t)(rowA + (QM) * 64 + _i * 16) * 64 + (cX ^ (_k * 32)));     \
} while (0)

#define READB(PAN, QN) do {                                                    \
    _Pragma("unroll") for (int _n = 0; _n < 2; ++_n)                           \
    _Pragma("unroll") for (int _k = 0; _k < 2; ++_k)                           \
        bf[(QN) * 2 + _n][_k] = *(const bf16x8*)((PAN) +                       \
            (size_t)(rowB + (QN) * 32 + _n * 16) * 64 + (cX ^ (_k * 32)));     \
} while (0)

#define MFMA16(QM, QN)                                                         \
    _Pragma("unroll") for (int _i = 0; _i < 4; ++_i)                           \
    _Pragma("unroll") for (int _n = 0; _n < 2; ++_n)                           \
    _Pragma("unroll") for (int _k = 0; _k < 2; ++_k)                           \
        acc[(QM) * 4 + _i][(QN) * 2 + _n] =                                    \
            __builtin_amdgcn_mfma_f32_16x16x32_bf16(                           \
                af[_i][_k], bf[(QN) * 2 + _n][_k],                             \
                acc[(QM) * 4 + _i][(QN) * 2 + _n], 0, 0, 0)

#define PH_SYNC do {                                                           \
    __builtin_amdgcn_s_barrier();                                              \
    asm volatile("s_waitcnt lgkmcnt(0)" ::: "memory");                         \
    __builtin_amdgcn_sched_barrier(0);                                         \
    __builtin_amdgcn_s_setprio(1);                                             \
} while (0)

#define PH_END do {                                                            \
    __builtin_amdgcn_s_setprio(0);                                             \
    __builtin_amdgcn_s_barrier();                                              \
} while (0)

#define PH_END_VM do {                                                         \
    __builtin_amdgcn_s_setprio(0);                                             \
    asm volatile("s_waitcnt vmcnt(4)" ::: "memory");                           \
    __builtin_amdgcn_s_barrier();                                              \
} while (0)

__global__ __launch_bounds__(512) void rbf_gemm(
        const ushort* __restrict__ Cb,  // centers bf16 [TN][TK]
        const ushort* __restrict__ Xb,  // input   bf16 [TM][TK]
        const float* __restrict__ xsq,
        const float* __restrict__ csq,
        const float* __restrict__ fsc,
        float* __restrict__ out) {
    __shared__ __align__(16) ushort lds[65536];  // 128 KiB

    // XCD swizzle, bm-major chunks (r2 mapping): per XCD, 128 contiguous wgs
    // = 8 input tiles x all 16 center tiles -> input panel L2-shared 16x.
    const int bid = blockIdx.x;
    const int wg = (bid & 7) * 128 + (bid >> 3);
    const int bm = wg >> 4;   // 64 input tiles (rows of out)
    const int bn = wg & 15;   // 16 center tiles (cols of out)
    const int rowx0 = bm * 256;

    const int tid = threadIdx.x;
    const int lane = tid & 63, wave = tid >> 6;
    const int wr = wave >> 2, wc = wave & 3;      // wr: centers-dim, wc: input-dim
    const int lrow = lane & 15, lhi = lane >> 4;  // MFMA fragment coords
    const int cX = (lhi * 8) ^ ((lrow & 4) << 2) ^ ((lrow & 8) << 2);
    const int rowA = wr * 128 + lrow;             // centers panel row
    const int rowB = wc * 64 + lrow;              // input panel row
    const int wbase = wave * 512;                 // elems: wave's 1KB staging slice

    // Per-lane staging source: linear LDS slot -> inverse-swizzled global col.
    const int srow = tid >> 3;
    const int scol = ((tid & 7) * 8) ^ ((tid & 32) >> 1) ^ ((tid & 64) >> 1);
    const ushort* gAl = Cb + (size_t)(bn * 256 + srow) * TK + scol;   // centers
    const ushort* gBl = Xb + (size_t)(rowx0 + srow) * TK + scol;      // input

    ushort* pA0 = lds;           // buf0 A (even K-tiles)
    ushort* pB0 = lds + 16384;   // buf0 B
    ushort* pA1 = lds + 32768;   // buf1 A (odd K-tiles)
    ushort* pB1 = lds + 49152;   // buf1 B

    bf16x8 af[4][2];  // current A (centers) quadrant
    bf16x8 bf[4][2];  // all B (input) frags for current tile

    f32x4 acc[8][4];
#pragma unroll
    for (int m = 0; m < 8; ++m)
#pragma unroll
        for (int n = 0; n < 4; ++n)
            acc[m][n] = (f32x4){0.f, 0.f, 0.f, 0.f};

    // Prologue: B(0), A(0), B(1) (12 insts); vmcnt(4) retires B(0)+A(0),
    // leaves B(1) in flight.
    STAGE(pB0, BSRC(0), 0); STAGE(pB0, BSRC(0), 1);
    STAGE(pA0, ASRC(0), 0); STAGE(pA0, ASRC(0), 1);
    STAGE(pB1, BSRC(1), 0); STAGE(pB1, BSRC(1), 1);
    asm volatile("s_waitcnt vmcnt(4)" ::: "memory");
    __builtin_amdgcn_s_barrier();

#pragma unroll 1
    for (int t = 0; t < NT; t += 2) {
        // ---- tile t (buf0) ----
        READA(pA0, 0); READB(pB0, 0);
        STAGE(pA1, ASRC(t + 1), 0);
        PH_SYNC; MFMA16(0, 0); PH_END;

        READB(pB0, 1);
        STAGE(pA1, ASRC(t + 1), 1);
        PH_SYNC; MFMA16(0, 1); PH_END;

        READA(pA0, 1);
        STAGE(pB0, BSRC(t + 2), 0);
        PH_SYNC; MFMA16(1, 0); PH_END;

        STAGE(pB0, BSRC(t + 2), 1);
        PH_SYNC; MFMA16(1, 1); PH_END_VM;   // retires B(t+1)+A(t+1), leaves B(t+2)

        // ---- tile t+1 (buf1) ----
        READA(pA1, 0); READB(pB1, 0);
        STAGE(pA0, ASRC(t + 2), 0);
        PH_SYNC; MFMA16(0, 0); PH_END;

        READB(pB1, 1);
        STAGE(pA0, ASRC(t + 2), 1);
        PH_SYNC; MFMA16(0, 1); PH_END;

        READA(pA1, 1);
        STAGE(pB1, BSRC(t + 3), 0);
        PH_SYNC; MFMA16(1, 0); PH_END;

        STAGE(pB1, BSRC(t + 3), 1);
        PH_SYNC; MFMA16(1, 1); PH_END_VM;   // retires B(t+2)+A(t+2), leaves B(t+3)
    }

    // Epilogue (once per block): acc[m][n][jj] = cross[o][b],
    //   o = o0 + m*16 + lhi*4 + jj (centers), b = b0 + n*16 + lrow (input).
    // Contiguous f32x4 stores; they drain while the next block launches.
    const int o0 = bn * 256 + wr * 128;
    const int b0 = rowx0 + wc * 64;
#pragma unroll
    for (int m = 0; m < 8; ++m) {
        const int o4 = o0 + m * 16 + lhi * 4;
        const f32x4 cs4 = *(const f32x4*)(csq + o4);
        const f32x4 fs4 = *(const f32x4*)(fsc + o4);
#pragma unroll
        for (int n = 0; n < 4; ++n) {
            const int b = b0 + n * 16 + lrow;
            const float xs = xsq[b];
            f32x4 v;
#pragma unroll
            for (int jj = 0; jj < 4; ++jj) {
                float d2 = fmaxf(xs + cs4[jj] - 2.0f * acc[m][n][jj], 0.0f);
                v[jj] = __expf(fs4[jj] * d2);
            }
            *(f32x4*)(out + (size_t)b * TN + o4) = v;
        }
    }
}

extern "C" void kernel_launch(void* const* d_in, const int* in_sizes, int n_in,
                              void* d_out, int out_size, void* d_ws, size_t ws_size,
                              hipStream_t stream) {
    const float* inp = (const float*)d_in[0];  // [TM, TK]
    const float* ctr = (const float*)d_in[1];  // [TN, TK]
    const float* ls  = (const float*)d_in[2];  // [TN]
    float* out = (float*)d_out;

    // workspace layout (~42 MB)
    ushort* Abf = (ushort*)d_ws;
    ushort* Bbf = Abf + (size_t)TM * TK;
    float* xsq = (float*)(Bbf + (size_t)TN * TK);
    float* csq = xsq + TM;
    float* fsc = csq + TN;

    rowsq_cvt<<<TM, 256, 0, stream>>>(inp, Abf, xsq);
    rowsq_cvt<<<TN, 256, 0, stream>>>(ctr, Bbf, csq);
    scale_k<<<(TN + 255) / 256, 256, 0, stream>>>(ls, fsc);

    rbf_gemm<<<(TM / 256) * (TN / 256), 512, 0, stream>>>(Bbf, Abf, xsq, csq, fsc, out);
}